// Round 7
// baseline (460.074 us; speedup 1.0000x reference)
//
#include <hip/hip_runtime.h>

#define K_TAGS 50
#define T_MAX 256
#define START_TAG 48
#define END_TAG 49
#define LOG2E 1.4426950408889634f
#define LN2 0.6931471805599453f
#define KK 2500    // dwords per 50x50 step matrix
#define GPAD 53    // padded Gt row stride (odd => conflict-free strided access)

// hardware transcendentals: v_exp_f32 is 2^x, v_log_f32 is log2(x)
#define EXP2F(x) __builtin_amdgcn_exp2f(x)
#define LOG2F(x) __builtin_amdgcn_logf(x)

__device__ __forceinline__ float rdlane(float v, int i) {
    return __int_as_float(__builtin_amdgcn_readlane(__float_as_int(v), i));
}

// Raw barrier with LDS-only drain (0xC07F = vmcnt(63) expcnt(7) lgkmcnt(0)).
// Builtin, not inline asm (rounds 2/3: asm "memory" clobber => full vm drain).
__device__ __forceinline__ void barrier_lds() {
    __builtin_amdgcn_sched_barrier(0);
    __builtin_amdgcn_s_waitcnt(0xC07F);
    __builtin_amdgcn_s_barrier();
    __builtin_amdgcn_sched_barrier(0);
}

// SYMMETRIC SPLIT-i (round-4 structure, 89us) with 4 surgical changes:
//  1. rescale only every 4th step (fp32 headroom: growth ~2^7/step, 4 steps
//     from a 2^14 base stays < 2^60; non-rescale combine = plain sum).
//  2. pbuf layout [jc*4+wave]: combine = ONE ds_read_b128 instead of 4 b32.
//  3. segment re-phased: [FMA(s) | pbuf-write | (bwd) Gt-write] BARRIER
//     [pbuf-read || loads(s+4) || exp || (bwd) Gt-read] -> sum. Staging issue
//     now hides inside the pbuf-read latency shadow instead of delaying it.
//  4. backward made EXACT (v <- G'v, was G'^T v): per step the wave's 13
//     exp'd rows go to LDS Gt[row][col] (pad-53, conflict-free), and the FMA
//     reads G'[jc][rb+r] = Gt[jc*GPAD+rb+r]. Writes/reads are both off the
//     serial path (write pre-barrier, read issued in the latency shadow for
//     the NEXT step). Split biased 9:16 fwd since bwd carries the LDS work.
// (Round-6 resubmission: previous bench died to a container-acquisition
//  failure, not a kernel fault — audited barrier/race/resource safety.)
__global__ __launch_bounds__(256, 1) void crf_fwd_kernel(
    const float* __restrict__ scores, const int* __restrict__ targets,
    const int* __restrict__ lengths, float* __restrict__ accum,
    float* __restrict__ uv)
{
    const int b    = blockIdx.x >> 1;
    const int dir  = blockIdx.x & 1;      // 0 = forward, 1 = backward
    const int tid  = threadIdx.x;
    const int wave = tid >> 6;
    const int lane = tid & 63;
    const int len  = lengths[b];
    const float* __restrict__ sp = scores + (size_t)b * T_MAX * KK;
    const int jc = (lane < K_TAGS) ? lane : (K_TAGS - 1);
    const int rb = 13 * wave;             // owned slice [rb, rb+13)

    __shared__ float Gt[2][K_TAGS * GPAD];          // bwd: exp'd G, natural layout
    __shared__ __align__(16) float pbuf[2][256];    // partials, [jc*4 + wave]

    const int m = (len >= 2) ? (((len - 2) * 9) >> 4) : 0;  // fwd steps 1..m
    int count = dir ? (len - 2 - m) : m;
    if (count < 0) count = 0;

    // ---- gold score: fwd block only, one timestep per thread ----
    if (dir == 0) {
        float g = 0.f;
        if (tid < len) g = sp[(size_t)tid * KK + targets[b * T_MAX + tid]];
        #pragma unroll
        for (int off = 32; off; off >>= 1) g += __shfl_down(g, off, 64);
        if (lane == 0) atomicAdd(&accum[1], g);
    }

    // ---- init L/M (replicated per wave); true log2-value = M + log2(L) ----
    float L, M;
    if (dir == 0) {
        float bc = sp[START_TAG * K_TAGS + jc] * LOG2E;   // alpha0 row
        M = rdlane(bc, 0);
        L = EXP2F(bc - M);
    } else {
        M = 0.f;
        L = (len >= 2)
            ? EXP2F(sp[(size_t)(len - 1) * KK + jc * K_TAGS + END_TAG] * LOG2E)
            : ((jc == END_TAG) ? 1.f : 0.f);
    }

    if (count > 0) {
        float S[4][13];           // raw-score load pipeline (step q <-> set q&3)
        float P[2][13];           // fwd: exp'd operand double buffer
                                  // bwd: P[0]=exp staging (E), P[1]=Gt read buf (R)
        auto tof = [&](int s) {
            int ss = (s <= count) ? s : count;            // clamp; surplus unused
            return dir ? (len - 1 - ss) : ss;
        };
        auto loadset = [&](int set, int s) {
            const float* p = sp + (size_t)tof(s) * KK + rb * K_TAGS + jc;
            #pragma unroll
            for (int r = 0; r < 13; ++r) S[set][r] = p[r * K_TAGS];
        };

        const int nseg = (count + 3) >> 2;

        if (dir == 0) {
            // ======================= forward =======================
            auto expset = [&](int pd, int set) {
                #pragma unroll
                for (int r = 0; r < 13; ++r) {
                    float e = EXP2F(S[set][r] * LOG2E);
                    if (r >= 11 && rb + r >= K_TAGS) e = 0.f;   // wave-3 dead rows
                    P[pd][r] = e;
                }
            };
            loadset(1, 1); loadset(2, 2); loadset(3, 3); loadset(0, 4);
            expset(1, 1);
            int st = 1;
            for (int g = 0; g < nseg; ++g) {
                #pragma unroll
                for (int u = 0; u < 4; ++u) {
                    const int  PP = (1 + u) & 1;        // st&1 (st ≡ 1+u mod 4)
                    const bool live = (st <= count);
                    if (live) {
                        float a0 = 0.f, a1 = 0.f, a2 = 0.f;
                        #pragma unroll
                        for (int r = 0; r < 13; r += 3) {
                            a0 = __builtin_fmaf(P[PP][r], rdlane(L, rb + r), a0);
                            if (r + 1 < 13)
                                a1 = __builtin_fmaf(P[PP][r + 1], rdlane(L, rb + r + 1), a1);
                            if (r + 2 < 13)
                                a2 = __builtin_fmaf(P[PP][r + 2], rdlane(L, rb + r + 2), a2);
                        }
                        if (lane < K_TAGS) pbuf[PP][jc * 4 + wave] = (a0 + a1) + a2;
                    }
                    barrier_lds();
                    if (live) {
                        float4 pv = *(const float4*)&pbuf[PP][jc * 4];
                        loadset((1 + u) & 3, st + 4);       // -> set st&3
                        expset(u & 1, (2 + u) & 3);         // exp(st+1)
                        float sum = (pv.x + pv.y) + (pv.z + pv.w);
                        if ((st & 3) == 0) {                // rescale every 4th
                            int ei = (__float_as_int(rdlane(sum, 0)) >> 23) & 0xFF;
                            float scale = __int_as_float((254 - ei) << 23);
                            L = sum * scale;
                            M += (float)(ei - 127);
                        } else L = sum;
                    }
                    ++st;
                }
            }
        } else {
            // ======================= backward (exact) =======================
            auto expE = [&](int set) {
                #pragma unroll
                for (int r = 0; r < 13; ++r) P[0][r] = EXP2F(S[set][r] * LOG2E);
            };
            auto writeGt = [&](int gpar) {
                float* g = Gt[gpar];
                #pragma unroll
                for (int r = 0; r < 13; ++r)
                    if (rb + r < K_TAGS && lane < K_TAGS)
                        g[(rb + r) * GPAD + jc] = P[0][r];
            };
            auto readR = [&](int gpar) {
                const float* g = Gt[gpar];
                #pragma unroll
                for (int r = 0; r < 13; ++r)
                    if (rb + r < K_TAGS) P[1][r] = g[jc * GPAD + rb + r];
            };
            // prologue: steps 1..5 staged; Gt[1]=G'(1); E=exp(2); R=G'(1) reads
            loadset(1, 1); loadset(2, 2); loadset(3, 3); loadset(0, 4);
            expE(1);
            writeGt(1);
            loadset(1, 5);
            expE(2);
            barrier_lds();
            readR(1);
            int st = 1;
            for (int g = 0; g < nseg; ++g) {
                #pragma unroll
                for (int u = 0; u < 4; ++u) {
                    const int  PP = (1 + u) & 1;        // st&1
                    const bool live = (st <= count);
                    if (live) {
                        float a0 = 0.f, a1 = 0.f, a2 = 0.f;
                        #pragma unroll
                        for (int r = 0; r < 13; r += 3) {
                            if (rb + r < K_TAGS)
                                a0 = __builtin_fmaf(P[1][r], rdlane(L, rb + r), a0);
                            if (r + 1 < 13 && rb + r + 1 < K_TAGS)
                                a1 = __builtin_fmaf(P[1][r + 1], rdlane(L, rb + r + 1), a1);
                            if (r + 2 < 13 && rb + r + 2 < K_TAGS)
                                a2 = __builtin_fmaf(P[1][r + 2], rdlane(L, rb + r + 2), a2);
                        }
                        if (lane < K_TAGS) pbuf[PP][jc * 4 + wave] = (a0 + a1) + a2;
                        writeGt(u & 1);                  // Gt[(st+1)&1] = G'(st+1)
                    }
                    barrier_lds();
                    if (live) {
                        float4 pv = *(const float4*)&pbuf[PP][jc * 4];
                        loadset((2 + u) & 3, st + 5);    // -> set (st+1)&3 (freed)
                        readR(u & 1);                    // R = G'(st+1) operands
                        expE((3 + u) & 3);               // E = exp(st+2)
                        float sum = (pv.x + pv.y) + (pv.z + pv.w);
                        if ((st & 3) == 0) {             // rescale every 4th
                            int ei = (__float_as_int(rdlane(sum, 0)) >> 23) & 0xFF;
                            float scale = __int_as_float((254 - ei) << 23);
                            L = sum * scale;
                            M += (float)(ei - 127);
                        } else L = sum;
                    }
                    ++st;
                }
            }
        }
    }

    // ---- publish result vector for the combine kernel ----
    if (wave == 0) {
        float* w = uv + (size_t)(dir ? (gridDim.x >> 1) + b : b) * 64;
        if (lane < K_TAGS) w[lane] = L;
        if (lane == 0)     w[K_TAGS] = M;
    }
}

// per-batch combine: Z_b = Mu + Mv + log2(sum_j u[j]*v[j])
__global__ void combine_kernel(const float* __restrict__ uv,
                               float* __restrict__ accum, int B)
{
    const int b = blockIdx.x, lane = threadIdx.x;
    const float* U = uv + (size_t)b * 64;
    const float* V = uv + (size_t)(B + b) * 64;
    float prod = (lane < K_TAGS) ? U[lane] * V[lane] : 0.f;
    #pragma unroll
    for (int off = 32; off; off >>= 1) prod += __shfl_down(prod, off, 64);
    if (lane == 0) {
        float z = (U[K_TAGS] + V[K_TAGS] + LOG2F(prod)) * LN2;
        atomicAdd(&accum[0], z);
    }
}

__global__ void finalize_kernel(const float* __restrict__ accum,
                                float* __restrict__ out, float invB)
{
    out[0] = (accum[0] - accum[1]) * invB;
}

extern "C" void kernel_launch(void* const* d_in, const int* in_sizes, int n_in,
                              void* d_out, int out_size, void* d_ws, size_t ws_size,
                              hipStream_t stream)
{
    const float* scores  = (const float*)d_in[0];
    const int*   targets = (const int*)d_in[1];
    const int*   lengths = (const int*)d_in[2];
    const int B = in_sizes[2];

    float* accum = (float*)d_ws;
    float* uv    = (float*)d_ws + 16;     // u[B][64] then v[B][64]
    hipMemsetAsync(accum, 0, 2 * sizeof(float), stream);
    crf_fwd_kernel<<<2 * B, 256, 0, stream>>>(scores, targets, lengths, accum, uv);
    combine_kernel<<<B, 64, 0, stream>>>(uv, accum, B);
    finalize_kernel<<<1, 1, 0, stream>>>(accum, (float*)d_out, 1.0f / (float)B);
}